// Round 1
// baseline (234.847 us; speedup 1.0000x reference)
//
#include <hip/hip_runtime.h>

#define E_TOTAL 800000
#define NN      50000
#define ND      64
#define ED      32
#define HD      128
#define OD      64
#define IND     160      // ED + 2*ND
#define MT      128      // edges per block
#define NTHREADS 512

typedef __attribute__((ext_vector_type(8))) short          short8;
typedef __attribute__((ext_vector_type(4))) float          f32x4;
typedef __attribute__((ext_vector_type(8))) unsigned short u16x8;
typedef __attribute__((ext_vector_type(4))) unsigned short u16x4;

__device__ __forceinline__ unsigned short f2bf(float f) {
  union { float f; unsigned u; } v; v.f = f;
  unsigned r = v.u + 0x7fffu + ((v.u >> 16) & 1u);   // round-to-nearest-even
  return (unsigned short)(r >> 16);
}

// ---- LDS geometry (u16 units). Padded strides: 168*2B=336B (20 dw mod 32 -> 8-bank
// period, 2-way conflict = free), 136*2B=272B (4-dw step, also 2-way). All row
// strides are multiples of 16B so ds_read_b128 stays aligned.
#define XS   168
#define HS   136
#define W1S  168
#define W2S  136
#define W1_OFF (MT * XS)                // 21504
#define W2_OFF (W1_OFF + HD * W1S)      // 43008
#define SMEM_U16 (W2_OFF + OD * W2S)    // 51712
#define SMEM_BYTES (SMEM_U16 * 2)       // 103424

// ---------- prepass: f32 -> bf16 node table ----------
__global__ void cvt_nodes(const float* __restrict__ in, unsigned short* __restrict__ out, int n4) {
  int i = blockIdx.x * blockDim.x + threadIdx.x;
  const int stride = gridDim.x * blockDim.x;
  for (; i < n4; i += stride) {
    float4 v = ((const float4*)in)[i];
    u16x4 o = { f2bf(v.x), f2bf(v.y), f2bf(v.z), f2bf(v.w) };
    ((u16x4*)out)[i] = o;
  }
}

// ---------- prepass: transpose + convert weights: wt[n][k] = bf16(w[k][n]) ----------
__global__ void transpose_w(const float* __restrict__ w, unsigned short* __restrict__ wt, int K, int N) {
  int i = blockIdx.x * blockDim.x + threadIdx.x;
  if (i >= K * N) return;
  int n = i / K;
  int k = i - n * K;
  wt[i] = f2bf(w[k * N + n]);
}

// ---------- main fused kernel ----------
// MFMA 16x16x32 bf16 layouts used (gfx950, per verified guide):
//   A: row = lane%16, k  = (lane/16)*8 + i   (8 contiguous bf16 -> ds_read_b128)
//   B: col = lane%16, k  = (lane/16)*8 + i   (weights stored transposed [n][k])
//   C/D: col = lane&15, row = (lane>>4)*4 + reg
__global__ __launch_bounds__(NTHREADS, 1)
void edge_mlp(const int* __restrict__ eidx,
              const float* __restrict__ ef,
              const unsigned short* __restrict__ nbf,
              const unsigned short* __restrict__ w1t,
              const unsigned short* __restrict__ w2t,
              const float* __restrict__ b1,
              const float* __restrict__ b2,
              float* __restrict__ out)
{
  extern __shared__ unsigned short sm[];
  unsigned short* X  = sm;             // [MT][XS]  (reused as H [MT][HS] after layer1)
  unsigned short* W1 = sm + W1_OFF;    // [HD][W1S]
  unsigned short* W2 = sm + W2_OFF;    // [OD][W2S]

  const int  tid = threadIdx.x;
  const long e0  = (long)blockIdx.x * MT;

  // ---- stage X: edge features (cvt), cols [0,32)
  for (int i = tid; i < MT * 8; i += NTHREADS) {
    const int row = i >> 3, c = i & 7;
    const float4 v = *(const float4*)(ef + (e0 + row) * ED + c * 4);
    u16x4 o = { f2bf(v.x), f2bf(v.y), f2bf(v.z), f2bf(v.w) };
    *(u16x4*)(X + row * XS + c * 4) = o;
  }
  // ---- stage X: src node gather (bf16 copy), cols [32,96)
  for (int i = tid; i < MT * 8; i += NTHREADS) {
    const int row = i >> 3, c = i & 7;
    int s = eidx[e0 + row];
    s = s < 0 ? 0 : (s >= NN ? NN - 1 : s);
    *(u16x8*)(X + row * XS + 32 + c * 8) = *(const u16x8*)(nbf + (long)s * ND + c * 8);
  }
  // ---- stage X: tgt node gather, cols [96,160)
  for (int i = tid; i < MT * 8; i += NTHREADS) {
    const int row = i >> 3, c = i & 7;
    int t = eidx[E_TOTAL + e0 + row];
    t = t < 0 ? 0 : (t >= NN ? NN - 1 : t);
    *(u16x8*)(X + row * XS + 96 + c * 8) = *(const u16x8*)(nbf + (long)t * ND + c * 8);
  }
  // ---- stage W1T [HD][IND]
  for (int i = tid; i < HD * (IND / 8); i += NTHREADS) {   // 2560 chunks
    const int row = i / 20, c = i - row * 20;
    *(u16x8*)(W1 + row * W1S + c * 8) = *(const u16x8*)(w1t + row * IND + c * 8);
  }
  // ---- stage W2T [OD][HD]
  for (int i = tid; i < OD * (HD / 8); i += NTHREADS) {    // 1024 chunks
    const int row = i >> 4, c = i & 15;
    *(u16x8*)(W2 + row * W2S + c * 8) = *(const u16x8*)(w2t + row * HD + c * 8);
  }
  __syncthreads();

  const int wid  = tid >> 6;       // 0..7, wave handles rows [16*wid, 16*wid+16)
  const int lane = tid & 63;
  const int lr   = lane & 15;
  const int lq   = lane >> 4;
  const int arow = wid * 16 + lr;

  float b1v[8];
  #pragma unroll
  for (int t = 0; t < 8; ++t) b1v[t] = b1[t * 16 + lr];

  f32x4 acc[8];
  #pragma unroll
  for (int t = 0; t < 8; ++t) acc[t] = (f32x4)0.0f;

  // ---- layer 1: H[128x128] = X[128x160] @ W1[160x128]
  #pragma unroll
  for (int ks = 0; ks < 5; ++ks) {
    const short8 a = *(const short8*)(X + arow * XS + ks * 32 + lq * 8);
    #pragma unroll
    for (int t = 0; t < 8; ++t) {
      const short8 b = *(const short8*)(W1 + (t * 16 + lr) * W1S + ks * 32 + lq * 8);
      acc[t] = __builtin_amdgcn_mfma_f32_16x16x32_bf16(a, b, acc[t], 0, 0, 0);
    }
  }
  __syncthreads();   // everyone done reading X -> safe to overlay with H

  // ---- relu + bias, convert to bf16, store H into LDS (overlay X)
  unsigned short* Hs = X;   // [MT][HS]
  #pragma unroll
  for (int t = 0; t < 8; ++t) {
    #pragma unroll
    for (int r = 0; r < 4; ++r) {
      const int m = wid * 16 + lq * 4 + r;
      float h = acc[t][r] + b1v[t];
      h = h > 0.0f ? h : 0.0f;
      Hs[m * HS + t * 16 + lr] = f2bf(h);
    }
  }
  __syncthreads();

  // ---- layer 2: OUT[128x64] = H[128x128] @ W2[128x64]
  float b2v[4];
  #pragma unroll
  for (int t = 0; t < 4; ++t) b2v[t] = b2[t * 16 + lr];
  f32x4 acc2[4];
  #pragma unroll
  for (int t = 0; t < 4; ++t) acc2[t] = (f32x4)0.0f;

  #pragma unroll
  for (int ks = 0; ks < 4; ++ks) {
    const short8 a = *(const short8*)(Hs + arow * HS + ks * 32 + lq * 8);
    #pragma unroll
    for (int t = 0; t < 4; ++t) {
      const short8 b = *(const short8*)(W2 + (t * 16 + lr) * W2S + ks * 32 + lq * 8);
      acc2[t] = __builtin_amdgcn_mfma_f32_16x16x32_bf16(a, b, acc2[t], 0, 0, 0);
    }
  }

  // ---- epilogue: bias + store f32
  #pragma unroll
  for (int t = 0; t < 4; ++t) {
    #pragma unroll
    for (int r = 0; r < 4; ++r) {
      const long m = e0 + wid * 16 + lq * 4 + r;
      out[m * OD + t * 16 + lr] = acc2[t][r] + b2v[t];
    }
  }
}

extern "C" void kernel_launch(void* const* d_in, const int* in_sizes, int n_in,
                              void* d_out, int out_size, void* d_ws, size_t ws_size,
                              hipStream_t stream) {
  const int*   eidx = (const int*)d_in[0];      // (2, E) int32 (JAX x64 disabled)
  const float* nf   = (const float*)d_in[1];    // (NN, 64)
  const float* ef   = (const float*)d_in[2];    // (E, 32)
  const float* w1   = (const float*)d_in[3];    // (160, 128)
  const float* b1   = (const float*)d_in[4];    // (128,)
  const float* w2   = (const float*)d_in[5];    // (128, 64)
  const float* b2   = (const float*)d_in[6];    // (64,)
  float*       out  = (float*)d_out;            // (E, 64)

  // workspace layout (u16): node table bf16, W1^T bf16, W2^T bf16
  unsigned short* nbf = (unsigned short*)d_ws;            // NN*ND   = 3,200,000
  unsigned short* w1t = nbf + (long)NN * ND;              // HD*IND  = 20,480
  unsigned short* w2t = w1t + (long)HD * IND;             // OD*HD   = 8,192

  cvt_nodes<<<1024, 256, 0, stream>>>(nf, nbf, (NN * ND) / 4);
  transpose_w<<<(HD * IND + 255) / 256, 256, 0, stream>>>(w1, w1t, IND, HD);
  transpose_w<<<(OD * HD + 255) / 256, 256, 0, stream>>>(w2, w2t, HD, OD);

  hipFuncSetAttribute((const void*)edge_mlp,
                      hipFuncAttributeMaxDynamicSharedMemorySize, SMEM_BYTES);
  edge_mlp<<<E_TOTAL / MT, NTHREADS, SMEM_BYTES, stream>>>(
      eidx, ef, nbf, w1t, w2t, b1, b2, out);
}

// Round 2
// 125.623 us; speedup vs baseline: 1.8695x; 1.8695x over previous
//
#include <hip/hip_runtime.h>

#define E_TOTAL 800000
#define NN      50000
#define ND      64
#define ED      32
#define HD      128
#define OD      64
#define IND     160      // ED + 2*ND
#define MT      128      // edges per block
#define NTHREADS 512

typedef __attribute__((ext_vector_type(8))) short          short8;
typedef __attribute__((ext_vector_type(4))) float          f32x4;
typedef __attribute__((ext_vector_type(8))) unsigned short u16x8;
typedef __attribute__((ext_vector_type(4))) unsigned short u16x4;

__device__ __forceinline__ unsigned short f2bf(float f) {
  union { float f; unsigned u; } v; v.f = f;
  unsigned r = v.u + 0x7fffu + ((v.u >> 16) & 1u);   // round-to-nearest-even
  return (unsigned short)(r >> 16);
}

// ======================= LDS layout: fragment-packed =======================
// A-fragment of 16x16x32 bf16 MFMA: lane l holds row (l&15), k = (l>>4)*8 + j.
// A frag for (m-tile wid, k-tile ks) lives at frag_id*1024B, lane l's 16B at
// frag_id*1024 + l*16.  All ds_read_b128 / ds_write_b128 then have consecutive
// lanes -> consecutive 16B -> ZERO bank conflicts, zero padding.
//   X  : 8 wid x 5 ks = 40 frags = 40960 B   (overlaid by H: 8 wid x 4 ks)
//   W1 : 5 ks x 8 t   = 40 frags = 40960 B   (B-frag: lane l = col (l&15), k)
// total = 81920 B exactly -> 2 blocks / CU (2 x 80 KiB = 160 KiB).
#define X_FRAGS   40
#define SMEM_U16  ((X_FRAGS + 40) * 512)
#define SMEM_BYTES (SMEM_U16 * 2)            // 81920

// ---------- prepass: f32 -> bf16 node table ----------
__global__ void cvt_nodes(const float* __restrict__ in, unsigned short* __restrict__ out, int n4) {
  int i = blockIdx.x * blockDim.x + threadIdx.x;
  const int stride = gridDim.x * blockDim.x;
  for (; i < n4; i += stride) {
    float4 v = ((const float4*)in)[i];
    u16x4 o = { f2bf(v.x), f2bf(v.y), f2bf(v.z), f2bf(v.w) };
    ((u16x4*)out)[i] = o;
  }
}

// ---------- prepass: pack W1 into B-fragment order ----------
// w1p[((ks*8+t)*64 + l)*8 + j] = bf16(w1[(ks*32 + (l>>4)*8 + j) * HD + t*16 + (l&15)])
__global__ void pack_w1(const float* __restrict__ w, unsigned short* __restrict__ out) {
  int i = blockIdx.x * blockDim.x + threadIdx.x;
  if (i >= HD * IND) return;
  int j = i & 7, l = (i >> 3) & 63, f = i >> 9;   // f in [0,40)
  int ks = f >> 3, t = f & 7;
  int k = ks * 32 + (l >> 4) * 8 + j;
  int n = t * 16 + (l & 15);
  out[i] = f2bf(w[k * HD + n]);
}

// ---------- prepass: pack W2 into B-fragment order ----------
__global__ void pack_w2(const float* __restrict__ w, unsigned short* __restrict__ out) {
  int i = blockIdx.x * blockDim.x + threadIdx.x;
  if (i >= OD * HD) return;
  int j = i & 7, l = (i >> 3) & 63, f = i >> 9;   // f in [0,16)
  int ks = f >> 2, t = f & 3;
  int k = ks * 32 + (l >> 4) * 8 + j;
  int n = t * 16 + (l & 15);
  out[i] = f2bf(w[k * OD + n]);
}

// ---------- main fused kernel ----------
__global__ __launch_bounds__(NTHREADS, 4)
void edge_mlp(const int* __restrict__ eidx,
              const float* __restrict__ ef,
              const unsigned short* __restrict__ nbf,
              const unsigned short* __restrict__ w1p,
              const unsigned short* __restrict__ w2p,
              const float* __restrict__ b1,
              const float* __restrict__ b2,
              float* __restrict__ out)
{
  extern __shared__ unsigned short sm[];
  unsigned short* Xs = sm;                 // 40 frags (H overlays frags 0..31)
  unsigned short* W1 = sm + X_FRAGS * 512; // 40 frags

  const int  tid  = threadIdx.x;
  const long e0   = (long)blockIdx.x * MT;
  const int  wid  = tid >> 6;
  const int  lane = tid & 63;
  const int  lq   = lane >> 4;
  const int  lr   = lane & 15;

  // ================= staging: issue ALL global loads first =================
  // edge features: frag (wid, ks=0). lane l covers row wid*16+(l&15),
  // k-chunk (l>>4)*8 -> 8 f32 -> 8 bf16.
  const int  erow = wid * 16 + lr;
  const float4 efv0 = *(const float4*)(ef + (e0 + erow) * ED + lq * 8);
  const float4 efv1 = *(const float4*)(ef + (e0 + erow) * ED + lq * 8 + 4);

  // src gathers: frags (w, ks=1+kss), i in [0,1024)
  u16x8 sv[2], tv[2];
  int   saddr[2], taddr[2];
  #pragma unroll
  for (int ii = 0; ii < 2; ++ii) {
    const int i = tid + ii * NTHREADS;
    const int f = i >> 6;                 // [0,16)
    const int w = f >> 1, kss = f & 1;
    const int l = i & 63;
    const int row = w * 16 + (l & 15);
    int s = eidx[e0 + row];
    s = s < 0 ? 0 : (s >= NN ? NN - 1 : s);
    sv[ii]   = *(const u16x8*)(nbf + (long)s * ND + kss * 32 + (l >> 4) * 8);
    saddr[ii] = ((w * 5 + 1 + kss) * 64 + l) * 8;
  }
  // tgt gathers: frags (w, ks=3+kss)
  #pragma unroll
  for (int ii = 0; ii < 2; ++ii) {
    const int i = tid + ii * NTHREADS;
    const int f = i >> 6;
    const int w = f >> 1, kss = f & 1;
    const int l = i & 63;
    const int row = w * 16 + (l & 15);
    int t = eidx[E_TOTAL + e0 + row];
    t = t < 0 ? 0 : (t >= NN ? NN - 1 : t);
    tv[ii]   = *(const u16x8*)(nbf + (long)t * ND + kss * 32 + (l >> 4) * 8);
    taddr[ii] = ((w * 5 + 3 + kss) * 64 + l) * 8;
  }
  // W1: 2560 16B chunks, 5 per thread, fully linear
  u16x8 wv[5];
  #pragma unroll
  for (int c = 0; c < 5; ++c)
    wv[c] = *(const u16x8*)(w1p + (tid + c * NTHREADS) * 8);

  // biases (L1-broadcast)
  float b1v[8];
  #pragma unroll
  for (int t = 0; t < 8; ++t) b1v[t] = b1[t * 16 + lr];
  float b2v[4];
  #pragma unroll
  for (int t = 0; t < 4; ++t) b2v[t] = b2[t * 16 + lr];

  // ================= ds_writes (all conflict-free b128) =================
  {
    u16x8 o = { f2bf(efv0.x), f2bf(efv0.y), f2bf(efv0.z), f2bf(efv0.w),
                f2bf(efv1.x), f2bf(efv1.y), f2bf(efv1.z), f2bf(efv1.w) };
    *(u16x8*)(Xs + (wid * 5 + 0) * 512 + lane * 8) = o;
  }
  #pragma unroll
  for (int ii = 0; ii < 2; ++ii) *(u16x8*)(Xs + saddr[ii]) = sv[ii];
  #pragma unroll
  for (int ii = 0; ii < 2; ++ii) *(u16x8*)(Xs + taddr[ii]) = tv[ii];
  #pragma unroll
  for (int c = 0; c < 5; ++c)
    *(u16x8*)(W1 + (tid + c * NTHREADS) * 8) = wv[c];

  __syncthreads();

  // ================= layer 1: H[128x128] = X @ W1 =================
  f32x4 acc[8];
  #pragma unroll
  for (int t = 0; t < 8; ++t) acc[t] = (f32x4)0.0f;

  #pragma unroll
  for (int ks = 0; ks < 5; ++ks) {
    const short8 a = *(const short8*)(Xs + (wid * 5 + ks) * 512 + lane * 8);
    #pragma unroll
    for (int t = 0; t < 8; ++t) {
      const short8 b = *(const short8*)(W1 + (ks * 8 + t) * 512 + lane * 8);
      acc[t] = __builtin_amdgcn_mfma_f32_16x16x32_bf16(a, b, acc[t], 0, 0, 0);
    }
  }
  __syncthreads();   // all waves done reading X -> overlay with H

  // ================= relu+bias -> H fragments (overlay X) =================
  // C/D: col = lane&15 (=lr), row = lq*4 + r  (within 16x16 tile t)
  // H element (m = wid*16+lq*4+r, k = t*16+lr) -> A-frag coords.
  #pragma unroll
  for (int t = 0; t < 8; ++t) {
    #pragma unroll
    for (int r = 0; r < 4; ++r) {
      float h = acc[t][r] + b1v[t];
      h = h > 0.0f ? h : 0.0f;
      const int k    = t * 16 + lr;
      const int frag = wid * 4 + (k >> 5);
      const int l2   = (((k >> 3) & 3) << 4) + lq * 4 + r;
      Xs[frag * 512 + l2 * 8 + (k & 7)] = f2bf(h);
    }
  }
  __syncthreads();

  // ================= layer 2: OUT[128x64] = H @ W2 =================
  short8 a2[4];
  #pragma unroll
  for (int ks = 0; ks < 4; ++ks)
    a2[ks] = *(const short8*)(Xs + (wid * 4 + ks) * 512 + lane * 8);

  f32x4 acc2[4];
  #pragma unroll
  for (int t = 0; t < 4; ++t) acc2[t] = (f32x4)0.0f;

  #pragma unroll
  for (int t = 0; t < 4; ++t) {
    #pragma unroll
    for (int ks = 0; ks < 4; ++ks) {
      const short8 b = *(const short8*)(w2p + ((ks * 4 + t) * 64 + lane) * 8);
      acc2[t] = __builtin_amdgcn_mfma_f32_16x16x32_bf16(a2[ks], b, acc2[t], 0, 0, 0);
    }
  }

  // ================= epilogue =================
  #pragma unroll
  for (int t = 0; t < 4; ++t) {
    #pragma unroll
    for (int r = 0; r < 4; ++r) {
      const long m = e0 + wid * 16 + lq * 4 + r;
      out[m * OD + t * 16 + lr] = acc2[t][r] + b2v[t];
    }
  }
}

extern "C" void kernel_launch(void* const* d_in, const int* in_sizes, int n_in,
                              void* d_out, int out_size, void* d_ws, size_t ws_size,
                              hipStream_t stream) {
  const int*   eidx = (const int*)d_in[0];      // (2, E) int32
  const float* nf   = (const float*)d_in[1];    // (NN, 64)
  const float* ef   = (const float*)d_in[2];    // (E, 32)
  const float* w1   = (const float*)d_in[3];    // (160, 128)
  const float* b1   = (const float*)d_in[4];    // (128,)
  const float* w2   = (const float*)d_in[5];    // (128, 64)
  const float* b2   = (const float*)d_in[6];    // (64,)
  float*       out  = (float*)d_out;            // (E, 64)

  unsigned short* nbf = (unsigned short*)d_ws;            // NN*ND
  unsigned short* w1p = nbf + (long)NN * ND;              // HD*IND
  unsigned short* w2p = w1p + (long)HD * IND;             // OD*HD

  cvt_nodes<<<1024, 256, 0, stream>>>(nf, nbf, (NN * ND) / 4);
  pack_w1<<<(HD * IND + 255) / 256, 256, 0, stream>>>(w1, w1p);
  pack_w2<<<(OD * HD + 255) / 256, 256, 0, stream>>>(w2, w2p);

  hipFuncSetAttribute((const void*)edge_mlp,
                      hipFuncAttributeMaxDynamicSharedMemorySize, SMEM_BYTES);
  edge_mlp<<<E_TOTAL / MT, NTHREADS, SMEM_BYTES, stream>>>(
      eidx, ef, nbf, w1p, w2p, b1, b2, out);
}